// Round 4
// baseline (201.029 us; speedup 1.0000x reference)
//
#include <hip/hip_runtime.h>
#include <stdint.h>

// Problem constants (fixed by reference setup_inputs)
#define NPOS 512   // N
#define NH   64    // H
#define NM   1024  // M
#define NB   256   // B
#define NM1  511   // N-1

typedef __attribute__((ext_vector_type(8)))  short bf16x8;
typedef __attribute__((ext_vector_type(16))) float f32x16;
typedef __attribute__((ext_vector_type(4)))  float f32x4;
typedef __attribute__((ext_vector_type(4)))  int   i32x4;

#if __has_builtin(__builtin_amdgcn_exp2f)
#define EXP2F(x) __builtin_amdgcn_exp2f(x)
#else
#define EXP2F(x) __expf((x) * 0.69314718055994531f)
#endif

__device__ __forceinline__ unsigned short f2bf(float x) {
    unsigned u = __float_as_uint(x);
    u = (u + 0x7FFFu + ((u >> 16) & 1u)) >> 16;   // RNE
    return (unsigned short)u;
}
__device__ __forceinline__ int pack2(unsigned short a, unsigned short b) {
    return (int)a | ((int)b << 16);
}

// ---------------- K0: sequences fp32 -> bf16 (exact for +/-1); zero output ---
__global__ __launch_bounds__(256, 4)
void k0_seq_bf16(const float* __restrict__ seq, unsigned short* __restrict__ seq_bf,
                 float* __restrict__ out) {
    if (blockIdx.x == 0 && threadIdx.x == 0) out[0] = 0.f;
    int idx = (blockIdx.x * 256 + threadIdx.x) * 4;
    f32x4 v = *(const f32x4*)(seq + idx);
    int2 o;
    o.x = pack2(f2bf(v.x), f2bf(v.y));
    o.y = pack2(f2bf(v.z), f2bf(v.w));
    *(int2*)(seq_bf + idx) = o;
}

// ---------------- K1a: Bn = softmax(B_logits, axis=-1), stored transposed ----
__global__ __launch_bounds__(64, 4)
void k1a_bnT(const float* __restrict__ Bl, float* __restrict__ BnT) {
    int h = blockIdx.x, l = threadIdx.x;
    float v[8]; float mx = -1e30f;
#pragma unroll
    for (int j = 0; j < 8; j++) { v[j] = Bl[h * NPOS + l + 64 * j]; mx = fmaxf(mx, v[j]); }
#pragma unroll
    for (int o = 32; o; o >>= 1) mx = fmaxf(mx, __shfl_xor(mx, o));
    float s = 0.f;
#pragma unroll
    for (int j = 0; j < 8; j++) { v[j] = __expf(v[j] - mx); s += v[j]; }
#pragma unroll
    for (int o = 32; o; o >>= 1) s += __shfl_xor(s, o);
    float r = 1.0f / s;
#pragma unroll
    for (int j = 0; j < 8; j++) BnT[(l + 64 * j) * NH + h] = v[j] * r;
}

// ---------------- K1b: phi_mu[m,h] = sum_n Bn[h,n]*memory[m,n] -> bf16 -------
// 4 m-rows per block (4x less BnT L2 traffic), 8 independent fma chains.
// Output is PRE-SCALED by log2(e) so K3 can use raw exp2.
__global__ __launch_bounds__(256, 4)
void k1b_phimu(const float* __restrict__ BnT, const float* __restrict__ mem,
               unsigned short* __restrict__ phimu) {
    const int m0 = blockIdx.x * 4, t = threadIdx.x;
    __shared__ float mrow[4][NPOS];
    __shared__ float part[4][256];
    {
        int row = t >> 6, c = (t & 63) * 8;
        const float* src = mem + (size_t)(m0 + row) * NPOS + c;
        *(f32x4*)(&mrow[row][c])     = *(const f32x4*)(src);
        *(f32x4*)(&mrow[row][c + 4]) = *(const f32x4*)(src + 4);
    }
    __syncthreads();
    const int h = t & 63, seg = t >> 6;
    float a[4] = {0.f, 0.f, 0.f, 0.f};
    float b2[4] = {0.f, 0.f, 0.f, 0.f};
    const float* bp = BnT + seg * 128 * NH + h;
#pragma unroll 4
    for (int nn = 0; nn < 128; nn += 2) {
        float x0 = bp[nn * NH], x1 = bp[(nn + 1) * NH];
#pragma unroll
        for (int row = 0; row < 4; row++) {
            a[row]  = fmaf(x0, mrow[row][seg * 128 + nn], a[row]);
            b2[row] = fmaf(x1, mrow[row][seg * 128 + nn + 1], b2[row]);
        }
    }
#pragma unroll
    for (int row = 0; row < 4; row++) part[row][t] = a[row] + b2[row];
    __syncthreads();
    if (t < 64) {
#pragma unroll
        for (int row = 0; row < 4; row++) {
            float s = (part[row][t] + part[row][t + 64]) + (part[row][t + 128] + part[row][t + 192]);
            phimu[(m0 + row) * NH + t] = f2bf(s * 1.4426950408889634f);  // * log2(e)
        }
    }
}

// ---------------- K1c: plusT[n][m] via LDS tile transpose (coalesced) --------
// grid 128: blockIdx = mt*8 + nt; 64x64 tile.
__global__ __launch_bounds__(256, 4)
void k1c_plusT(const float* __restrict__ mem, float* __restrict__ plusT) {
    __shared__ float sT[64][65];
    const int mt = blockIdx.x >> 3, nt = blockIdx.x & 7;
    const int t = threadIdx.x, rr = t >> 2, cc = t & 3;
    const float* src = mem + (size_t)(mt * 64 + rr) * NPOS + nt * 64 + cc * 16;
#pragma unroll
    for (int j = 0; j < 4; j++) {
        f32x4 v = *(const f32x4*)(src + j * 4);
        sT[rr][cc * 16 + j * 4 + 0] = (v.x > 0.f) ? 1.f : 0.f;
        sT[rr][cc * 16 + j * 4 + 1] = (v.y > 0.f) ? 1.f : 0.f;
        sT[rr][cc * 16 + j * 4 + 2] = (v.z > 0.f) ? 1.f : 0.f;
        sT[rr][cc * 16 + j * 4 + 3] = (v.w > 0.f) ? 1.f : 0.f;
    }
    __syncthreads();
    float* dst = plusT + (size_t)(nt * 64 + rr) * NM + mt * 64 + cc * 16;
#pragma unroll
    for (int j = 0; j < 4; j++) {
        f32x4 o;
        o.x = sT[cc * 16 + j * 4 + 0][rr];
        o.y = sT[cc * 16 + j * 4 + 1][rr];
        o.z = sT[cc * 16 + j * 4 + 2][rr];
        o.w = sT[cc * 16 + j * 4 + 3][rr];
        *(f32x4*)(dst + j * 4) = o;
    }
}

// ---------------- K2: fused masked-softmax + GEMM -> hat_phi (n,b,h) bf16 ----
// grid 511 (one block per n): A_logits read ONCE. Tile 256b x 64h, 4 waves.
// Pipelined: exp/stage(k) from regs | barrier | prefetch(k+1) + MFMA(k) | barrier.
__global__ __launch_bounds__(256, 2)
void k2_hatphi(const float* __restrict__ Al, const unsigned short* __restrict__ seq_bf,
               unsigned short* __restrict__ hatphi) {
    __shared__ __align__(16) unsigned short s_lds[256 * 72];  // S tile / out tile
    __shared__ __align__(16) unsigned short e_lds[64 * 72];   // exp(A) tile
    __shared__ float z_lds[64];                               // row sums Z[h]

    const int t = threadIdx.x;
    const int n = NM1 - (int)blockIdx.x;          // n in 1..511, big n first
    const int ksteps = (n + 63) >> 6;
    const int wv = t >> 6, lane = t & 63, half = lane >> 5, r = lane & 31;

    if (t < 64) z_lds[t] = 0.f;

    const int eh = t >> 2, ei = (t & 3) * 16;
    const float* arow = Al + ((size_t)n * NH + eh) * NPOS + ei;
    const unsigned short* srcS = seq_bf + (size_t)t * NPOS;

    f32x16 acc00, acc01, acc10, acc11;
#pragma unroll
    for (int i = 0; i < 16; i++) { acc00[i] = 0.f; acc01[i] = 0.f; acc10[i] = 0.f; acc11[i] = 0.f; }

    // prologue loads for k=0
    f32x4 ea[4]; i32x4 sa[8];
#pragma unroll
    for (int g = 0; g < 4; g++) ea[g] = *(const f32x4*)(arow + g * 4);
#pragma unroll
    for (int c = 0; c < 8; c++) sa[c] = *(const i32x4*)(srcS + c * 8);
    __syncthreads();   // z_lds init visible

    for (int kk = 0; kk < ksteps; kk++) {
        const int k0 = kk * 64;
        // exp + stage E tile from regs
        {
            float zp = 0.f;
            unsigned short* ep = e_lds + eh * 72 + ei;
#pragma unroll
            for (int g = 0; g < 4; g++) {
                int i0 = k0 + ei + g * 4;
                float e0 = (i0 + 0 < n) ? __expf(ea[g].x) : 0.f;
                float e1 = (i0 + 1 < n) ? __expf(ea[g].y) : 0.f;
                float e2 = (i0 + 2 < n) ? __expf(ea[g].z) : 0.f;
                float e3 = (i0 + 3 < n) ? __expf(ea[g].w) : 0.f;
                zp += (e0 + e1) + (e2 + e3);
                int2 o; o.x = pack2(f2bf(e0), f2bf(e1)); o.y = pack2(f2bf(e2), f2bf(e3));
                *(int2*)(ep + g * 4) = o;
            }
            zp += __shfl_xor(zp, 1);
            zp += __shfl_xor(zp, 2);
            if ((t & 3) == 0) z_lds[eh] += zp;
        }
        // stage S tile from regs (thread t owns row t, 64 bf16/kstep)
        {
            unsigned short* dp = s_lds + t * 72;
#pragma unroll
            for (int c = 0; c < 8; c++) *(i32x4*)(dp + c * 8) = sa[c];
        }
        __syncthreads();
        // prefetch k+1 (in flight during MFMA phase)
        if (kk + 1 < ksteps) {
#pragma unroll
            for (int g = 0; g < 4; g++) ea[g] = *(const f32x4*)(arow + k0 + 64 + g * 4);
#pragma unroll
            for (int c = 0; c < 8; c++) sa[c] = *(const i32x4*)(srcS + k0 + 64 + c * 8);
        }
        // MFMA: D[b][h] += S[b,i] * E[h,i]
        {
            const unsigned short* sA0 = s_lds + (wv * 64 + r) * 72;
            const unsigned short* sA1 = sA0 + 32 * 72;
            const unsigned short* sB0 = e_lds + r * 72;
            const unsigned short* sB1 = sB0 + 32 * 72;
#pragma unroll
            for (int kq = 0; kq < 4; kq++) {
                const int ko = kq * 16 + half * 8;
                bf16x8 A0 = *(const bf16x8*)(sA0 + ko);
                bf16x8 A1 = *(const bf16x8*)(sA1 + ko);
                bf16x8 B0 = *(const bf16x8*)(sB0 + ko);
                bf16x8 B1 = *(const bf16x8*)(sB1 + ko);
                acc00 = __builtin_amdgcn_mfma_f32_32x32x16_bf16(A0, B0, acc00, 0, 0, 0);
                acc01 = __builtin_amdgcn_mfma_f32_32x32x16_bf16(A0, B1, acc01, 0, 0, 0);
                acc10 = __builtin_amdgcn_mfma_f32_32x32x16_bf16(A1, B0, acc10, 0, 0, 0);
                acc11 = __builtin_amdgcn_mfma_f32_32x32x16_bf16(A1, B1, acc11, 0, 0, 0);
            }
        }
        __syncthreads();
    }
    // epilogue: scale by 1/Z[h], transpose through LDS, coalesced store (n,b,h)
    float rz0 = 1.0f / z_lds[r];
    float rz1 = 1.0f / z_lds[32 + r];
    unsigned short* o_lds = s_lds;  // safe: last barrier fenced MFMA reads
#pragma unroll
    for (int reg = 0; reg < 16; reg++) {
        int row = (reg & 3) + 8 * (reg >> 2) + 4 * half;
        o_lds[(wv * 64 + row) * 72 + r]            = f2bf(acc00[reg] * rz0);
        o_lds[(wv * 64 + row) * 72 + 32 + r]       = f2bf(acc01[reg] * rz1);
        o_lds[(wv * 64 + 32 + row) * 72 + r]       = f2bf(acc10[reg] * rz0);
        o_lds[(wv * 64 + 32 + row) * 72 + 32 + r]  = f2bf(acc11[reg] * rz1);
    }
    __syncthreads();
    {
        unsigned short* gp = hatphi + (size_t)(n - 1) * NB * NH + (size_t)t * NH;
        const unsigned short* lp = o_lds + t * 72;
#pragma unroll
        for (int c = 0; c < 8; c++) *(i32x4*)(gp + c * 8) = *(const i32x4*)(lp + c * 8);
    }
}

// ---------------- K3: retrieval softmax (no-max streaming) + BCE -------------
// Round-2 structure (best so far): grid (511,4), block = 4 waves, 64 b rows,
// m in 128-tiles split across waves (32 rows each), p prefetched 1 tile ahead.
// New: phimu pre-scaled by log2e -> single v_exp_f32 per element; den/num as
// f32x4 vector ops (v_pk_add/fma); adds pre-scaled mean directly to d_out.
__global__ __launch_bounds__(256, 4)
void k3_retrieve(const unsigned short* __restrict__ hatphi,
                 const unsigned short* __restrict__ phimu,
                 const float* __restrict__ plusT,
                 const float* __restrict__ seq,
                 float* __restrict__ out) {
    const int n = (int)blockIdx.x + 1;
    const int bblk = (int)blockIdx.y;
    const int t = threadIdx.x, wv = t >> 6, lane = t & 63, half = lane >> 5, r = lane & 31;

    __shared__ float s_plus[NM];
    __shared__ float dsum[4][64];
    __shared__ float nsum[4][64];

    bf16x8 q[2][4];
    {
        const unsigned short* qb = hatphi + (size_t)(n - 1) * NB * NH;
#pragma unroll
        for (int bs = 0; bs < 2; bs++)
#pragma unroll
            for (int kq = 0; kq < 4; kq++)
                q[bs][kq] = *(const bf16x8*)(qb + (bblk * 64 + bs * 32 + r) * NH + kq * 16 + half * 8);
    }
    // prefetch p tile 0
    bf16x8 p[4];
#pragma unroll
    for (int kq = 0; kq < 4; kq++)
        p[kq] = *(const bf16x8*)(phimu + (wv * 32 + r) * NH + kq * 16 + half * 8);
    // stage plus row (one dwordx4 per thread)
    *(f32x4*)(s_plus + t * 4) = *(const f32x4*)(plusT + n * NM + t * 4);
    __syncthreads();

    f32x4 den0 = {0.f,0.f,0.f,0.f}, num0 = {0.f,0.f,0.f,0.f};
    f32x4 den1 = {0.f,0.f,0.f,0.f}, num1 = {0.f,0.f,0.f,0.f};

    for (int it = 0; it < 8; ++it) {
        const int mb = it * 128 + wv * 32;
        bf16x8 pn[4];
        if (it < 7) {   // prefetch next tile (no barrier in loop: stays in flight)
#pragma unroll
            for (int kq = 0; kq < 4; kq++)
                pn[kq] = *(const bf16x8*)(phimu + (mb + 128 + r) * NH + kq * 16 + half * 8);
        }
        f32x16 a0, a1;
#pragma unroll
        for (int i = 0; i < 16; i++) { a0[i] = 0.f; a1[i] = 0.f; }
#pragma unroll
        for (int kq = 0; kq < 4; kq++) {
            a0 = __builtin_amdgcn_mfma_f32_32x32x16_bf16(p[kq], q[0][kq], a0, 0, 0, 0);
            a1 = __builtin_amdgcn_mfma_f32_32x32x16_bf16(p[kq], q[1][kq], a1, 0, 0, 0);
        }
        f32x4 pv[4];
#pragma unroll
        for (int g = 0; g < 4; g++) pv[g] = *(const f32x4*)(s_plus + mb + 4 * half + 8 * g);
#pragma unroll
        for (int g = 0; g < 4; g++) {
            f32x4 e0, e1;
#pragma unroll
            for (int j = 0; j < 4; j++) {
                e0[j] = EXP2F(a0[4 * g + j]);    // m = mb + j + 8*g + 4*half
                e1[j] = EXP2F(a1[4 * g + j]);
            }
            den0 += e0; num0 += e0 * pv[g];
            den1 += e1; num1 += e1 * pv[g];
        }
        if (it < 7) {
#pragma unroll
            for (int kq = 0; kq < 4; kq++) p[kq] = pn[kq];
        }
    }
    float d0 = (den0[0] + den0[1]) + (den0[2] + den0[3]);
    float nu0 = (num0[0] + num0[1]) + (num0[2] + num0[3]);
    float d1 = (den1[0] + den1[1]) + (den1[2] + den1[3]);
    float nu1 = (num1[0] + num1[1]) + (num1[2] + num1[3]);
    // combine the two m-halves (same b, complementary m rows)
    d0 += __shfl_xor(d0, 32); nu0 += __shfl_xor(nu0, 32);
    d1 += __shfl_xor(d1, 32); nu1 += __shfl_xor(nu1, 32);

    if (half == 0) {
        dsum[wv][r] = d0; dsum[wv][32 + r] = d1;
        nsum[wv][r] = nu0; nsum[wv][32 + r] = nu1;
    }
    __syncthreads();
    if (t < 64) {
        float d  = (dsum[0][t] + dsum[1][t]) + (dsum[2][t] + dsum[3][t]);
        float nu = (nsum[0][t] + nsum[1][t]) + (nsum[2][t] + nsum[3][t]);
        float p2 = nu / d;
        p2 = fminf(fmaxf(p2, 1e-6f), 1.0f - 1e-6f);
        float tg = seq[(size_t)(bblk * 64 + t) * NPOS + n];
        float bce = (tg > 0.f) ? -logf(p2) : -logf(1.0f - p2);
#pragma unroll
        for (int o = 32; o; o >>= 1) bce += __shfl_xor(bce, o);
        if (t == 0) atomicAdd(out, bce * (1.0f / 130816.0f));  // / (B*(N-1))
    }
}

extern "C" void kernel_launch(void* const* d_in, const int* in_sizes, int n_in,
                              void* d_out, int out_size, void* d_ws, size_t ws_size,
                              hipStream_t stream) {
    const float* seq = (const float*)d_in[0];  // (B,N)
    const float* mem = (const float*)d_in[1];  // (M,N)
    const float* Al  = (const float*)d_in[2];  // (N,H,N)
    const float* Bl  = (const float*)d_in[3];  // (H,N)

    char* ws = (char*)d_ws;
    unsigned short* seq_bf = (unsigned short*)(ws + 0);          // 256 KB
    float*          BnT    = (float*)(ws + 262144);              // 128 KB (N,H)
    unsigned short* phimu  = (unsigned short*)(ws + 393216);     // 128 KB (M,H) *log2e
    float*          plusT  = (float*)(ws + 524288);              // 2 MB (N,M)
    unsigned short* hatphi = (unsigned short*)(ws + 2621440);    // 16.7 MB (N-1,B,H)
    float*          outp   = (float*)d_out;

    k0_seq_bf16<<<128, 256, 0, stream>>>(seq, seq_bf, outp);
    k1a_bnT<<<64, 64, 0, stream>>>(Bl, BnT);
    k1b_phimu<<<256, 256, 0, stream>>>(BnT, mem, phimu);
    k1c_plusT<<<128, 256, 0, stream>>>(mem, plusT);
    k2_hatphi<<<511, 256, 0, stream>>>(Al, seq_bf, hatphi);
    k3_retrieve<<<dim3(511, 4), 256, 0, stream>>>(hatphi, phimu, plusT, seq, outp);
}

// Round 5
// 164.866 us; speedup vs baseline: 1.2193x; 1.2193x over previous
//
#include <hip/hip_runtime.h>
#include <stdint.h>

// Problem constants (fixed by reference setup_inputs)
#define NPOS 512   // N
#define NH   64    // H
#define NM   1024  // M
#define NB   256   // B
#define NM1  511   // N-1

typedef __attribute__((ext_vector_type(8)))  short bf16x8;
typedef __attribute__((ext_vector_type(16))) float f32x16;
typedef __attribute__((ext_vector_type(4)))  float f32x4;
typedef __attribute__((ext_vector_type(4)))  int   i32x4;

#if __has_builtin(__builtin_amdgcn_exp2f)
#define EXP2F(x) __builtin_amdgcn_exp2f(x)
#else
#define EXP2F(x) __expf((x) * 0.69314718055994531f)
#endif

__device__ __forceinline__ unsigned short f2bf(float x) {
    unsigned u = __float_as_uint(x);
    u = (u + 0x7FFFu + ((u >> 16) & 1u)) >> 16;   // RNE
    return (unsigned short)u;
}
__device__ __forceinline__ int pack2(unsigned short a, unsigned short b) {
    return (int)a | ((int)b << 16);
}

// ---------------- K0: sequences fp32 -> bf16 (exact for +/-1); zero output ---
__global__ __launch_bounds__(256, 4)
void k0_seq_bf16(const float* __restrict__ seq, unsigned short* __restrict__ seq_bf,
                 float* __restrict__ out) {
    if (blockIdx.x == 0 && threadIdx.x == 0) out[0] = 0.f;
    int idx = (blockIdx.x * 256 + threadIdx.x) * 4;
    f32x4 v = *(const f32x4*)(seq + idx);
    int2 o;
    o.x = pack2(f2bf(v.x), f2bf(v.y));
    o.y = pack2(f2bf(v.z), f2bf(v.w));
    *(int2*)(seq_bf + idx) = o;
}

// ---------------- K1a: Bn = softmax(B_logits, axis=-1), stored transposed ----
__global__ __launch_bounds__(64, 4)
void k1a_bnT(const float* __restrict__ Bl, float* __restrict__ BnT) {
    int h = blockIdx.x, l = threadIdx.x;
    float v[8]; float mx = -1e30f;
#pragma unroll
    for (int j = 0; j < 8; j++) { v[j] = Bl[h * NPOS + l + 64 * j]; mx = fmaxf(mx, v[j]); }
#pragma unroll
    for (int o = 32; o; o >>= 1) mx = fmaxf(mx, __shfl_xor(mx, o));
    float s = 0.f;
#pragma unroll
    for (int j = 0; j < 8; j++) { v[j] = __expf(v[j] - mx); s += v[j]; }
#pragma unroll
    for (int o = 32; o; o >>= 1) s += __shfl_xor(s, o);
    float r = 1.0f / s;
#pragma unroll
    for (int j = 0; j < 8; j++) BnT[(l + 64 * j) * NH + h] = v[j] * r;
}

// ---------------- K1b: phi_mu[m,h] = sum_n Bn[h,n]*memory[m,n] -> bf16 -------
// 512 blocks x 2 m-rows (2 blocks/CU), 4 independent fma chains.
// Output is PRE-SCALED by log2(e) so K3 can use raw exp2.
__global__ __launch_bounds__(256, 4)
void k1b_phimu(const float* __restrict__ BnT, const float* __restrict__ mem,
               unsigned short* __restrict__ phimu) {
    const int m0 = blockIdx.x * 2, t = threadIdx.x;
    __shared__ float mrow[2][NPOS];
    __shared__ float part[2][256];
    {
        int row = t >> 7, c = (t & 127) * 4;
        *(f32x4*)(&mrow[row][c]) = *(const f32x4*)(mem + (size_t)(m0 + row) * NPOS + c);
    }
    __syncthreads();
    const int h = t & 63, seg = t >> 6;
    float a[2] = {0.f, 0.f};
    float b2[2] = {0.f, 0.f};
    const float* bp = BnT + seg * 128 * NH + h;
#pragma unroll 8
    for (int nn = 0; nn < 128; nn += 2) {
        float x0 = bp[nn * NH], x1 = bp[(nn + 1) * NH];
#pragma unroll
        for (int row = 0; row < 2; row++) {
            a[row]  = fmaf(x0, mrow[row][seg * 128 + nn], a[row]);
            b2[row] = fmaf(x1, mrow[row][seg * 128 + nn + 1], b2[row]);
        }
    }
#pragma unroll
    for (int row = 0; row < 2; row++) part[row][t] = a[row] + b2[row];
    __syncthreads();
    if (t < 64) {
#pragma unroll
        for (int row = 0; row < 2; row++) {
            float s = (part[row][t] + part[row][t + 64]) + (part[row][t + 128] + part[row][t + 192]);
            phimu[(m0 + row) * NH + t] = f2bf(s * 1.4426950408889634f);  // * log2(e)
        }
    }
}

// ---------------- K1c: plusT[n][m] via LDS tile transpose (coalesced) --------
// grid 128: blockIdx = mt*8 + nt; 64x64 tile.
__global__ __launch_bounds__(256, 4)
void k1c_plusT(const float* __restrict__ mem, float* __restrict__ plusT) {
    __shared__ float sT[64][65];
    const int mt = blockIdx.x >> 3, nt = blockIdx.x & 7;
    const int t = threadIdx.x, rr = t >> 2, cc = t & 3;
    const float* src = mem + (size_t)(mt * 64 + rr) * NPOS + nt * 64 + cc * 16;
#pragma unroll
    for (int j = 0; j < 4; j++) {
        f32x4 v = *(const f32x4*)(src + j * 4);
        sT[rr][cc * 16 + j * 4 + 0] = (v.x > 0.f) ? 1.f : 0.f;
        sT[rr][cc * 16 + j * 4 + 1] = (v.y > 0.f) ? 1.f : 0.f;
        sT[rr][cc * 16 + j * 4 + 2] = (v.z > 0.f) ? 1.f : 0.f;
        sT[rr][cc * 16 + j * 4 + 3] = (v.w > 0.f) ? 1.f : 0.f;
    }
    __syncthreads();
    float* dst = plusT + (size_t)(nt * 64 + rr) * NM + mt * 64 + cc * 16;
#pragma unroll
    for (int j = 0; j < 4; j++) {
        f32x4 o;
        o.x = sT[cc * 16 + j * 4 + 0][rr];
        o.y = sT[cc * 16 + j * 4 + 1][rr];
        o.z = sT[cc * 16 + j * 4 + 2][rr];
        o.w = sT[cc * 16 + j * 4 + 3][rr];
        *(f32x4*)(dst + j * 4) = o;
    }
}

// ---------------- K2: fused masked-softmax + GEMM -> hat_phi (n,b,h) bf16 ----
// grid (2, 511): x = b-block of 128, y -> n. Block 256 thr, out tile 128b x 64h.
// Pipelined: exp/stage(k) | barrier | prefetch(k+1) + MFMA(k) | barrier.
__global__ __launch_bounds__(256, 3)
void k2_hatphi(const float* __restrict__ Al, const unsigned short* __restrict__ seq_bf,
               unsigned short* __restrict__ hatphi) {
    __shared__ __align__(16) unsigned short s_lds[128 * 72];  // S tile / out tile
    __shared__ __align__(16) unsigned short e_lds[64 * 72];   // exp(A) tile
    __shared__ float z_lds[64];                               // row sums Z[h]

    const int t = threadIdx.x;
    const int n = NM1 - (int)blockIdx.y;          // n in 1..511, big n first
    const int bblk = (int)blockIdx.x;             // 0 or 1
    const int ksteps = (n + 63) >> 6;
    const int wv = t >> 6, lane = t & 63, half = lane >> 5, r = lane & 31;

    if (t < 64) z_lds[t] = 0.f;

    const int eh = t >> 2, ei = (t & 3) * 16;
    const float* arow = Al + ((size_t)n * NH + eh) * NPOS + ei;
    const int srow = t >> 1, scol = (t & 1) * 32;
    const unsigned short* srcS = seq_bf + (size_t)(bblk * 128 + srow) * NPOS + scol;

    f32x16 acc0, acc1;
#pragma unroll
    for (int i = 0; i < 16; i++) { acc0[i] = 0.f; acc1[i] = 0.f; }

    // prologue loads for k=0
    f32x4 ea[4]; i32x4 sa[4];
#pragma unroll
    for (int g = 0; g < 4; g++) ea[g] = *(const f32x4*)(arow + g * 4);
#pragma unroll
    for (int c = 0; c < 4; c++) sa[c] = *(const i32x4*)(srcS + c * 8);
    __syncthreads();   // z_lds init visible

    for (int kk = 0; kk < ksteps; kk++) {
        const int k0 = kk * 64;
        // exp + stage E tile from regs
        {
            float zp = 0.f;
            unsigned short* ep = e_lds + eh * 72 + ei;
#pragma unroll
            for (int g = 0; g < 4; g++) {
                int i0 = k0 + ei + g * 4;
                float e0 = (i0 + 0 < n) ? __expf(ea[g].x) : 0.f;
                float e1 = (i0 + 1 < n) ? __expf(ea[g].y) : 0.f;
                float e2 = (i0 + 2 < n) ? __expf(ea[g].z) : 0.f;
                float e3 = (i0 + 3 < n) ? __expf(ea[g].w) : 0.f;
                zp += (e0 + e1) + (e2 + e3);
                int2 o; o.x = pack2(f2bf(e0), f2bf(e1)); o.y = pack2(f2bf(e2), f2bf(e3));
                *(int2*)(ep + g * 4) = o;
            }
            zp += __shfl_xor(zp, 1);
            zp += __shfl_xor(zp, 2);
            if ((t & 3) == 0) z_lds[eh] += zp;
        }
        // stage S tile from regs
        {
            unsigned short* dp = s_lds + srow * 72 + scol;
#pragma unroll
            for (int c = 0; c < 4; c++) *(i32x4*)(dp + c * 8) = sa[c];
        }
        __syncthreads();
        // prefetch k+1 (in flight during MFMA phase)
        if (kk + 1 < ksteps) {
#pragma unroll
            for (int g = 0; g < 4; g++) ea[g] = *(const f32x4*)(arow + k0 + 64 + g * 4);
#pragma unroll
            for (int c = 0; c < 4; c++) sa[c] = *(const i32x4*)(srcS + k0 + 64 + c * 8);
        }
        // MFMA: D[b][h] += S[b,i] * E[h,i]
        {
            const unsigned short* sA  = s_lds + (wv * 32 + r) * 72;
            const unsigned short* sB0 = e_lds + r * 72;
            const unsigned short* sB1 = sB0 + 32 * 72;
#pragma unroll
            for (int kq = 0; kq < 4; kq++) {
                const int ko = kq * 16 + half * 8;
                bf16x8 A  = *(const bf16x8*)(sA + ko);
                bf16x8 B0 = *(const bf16x8*)(sB0 + ko);
                bf16x8 B1 = *(const bf16x8*)(sB1 + ko);
                acc0 = __builtin_amdgcn_mfma_f32_32x32x16_bf16(A, B0, acc0, 0, 0, 0);
                acc1 = __builtin_amdgcn_mfma_f32_32x32x16_bf16(A, B1, acc1, 0, 0, 0);
            }
        }
        __syncthreads();
    }
    // epilogue: scale by 1/Z[h], transpose through LDS, coalesced store (n,b,h)
    float rz0 = 1.0f / z_lds[r];
    float rz1 = 1.0f / z_lds[32 + r];
    unsigned short* o_lds = s_lds;  // safe: last barrier fenced MFMA reads
#pragma unroll
    for (int reg = 0; reg < 16; reg++) {
        int row = (reg & 3) + 8 * (reg >> 2) + 4 * half;
        o_lds[(wv * 32 + row) * 72 + r]      = f2bf(acc0[reg] * rz0);
        o_lds[(wv * 32 + row) * 72 + 32 + r] = f2bf(acc1[reg] * rz1);
    }
    __syncthreads();
    {
        unsigned short* gp = hatphi + (size_t)(n - 1) * NB * NH + (size_t)(bblk * 128 + srow) * NH + scol;
        const unsigned short* lp = o_lds + srow * 72 + scol;
#pragma unroll
        for (int c = 0; c < 4; c++) *(i32x4*)(gp + c * 8) = *(const i32x4*)(lp + c * 8);
    }
}

// ---------------- K3: retrieval softmax (no-max streaming) + BCE -------------
// R2 register regime (lb(256,3) -> VGPR ~84, NO SPILLS) + exp2 trick + packed
// f32x4 accumulate. grid (511,4), block = 4 waves, 64 b rows, m in 128-tiles
// split across waves (32 rows each), p prefetched 1 tile ahead.
__global__ __launch_bounds__(256, 3)
void k3_retrieve(const unsigned short* __restrict__ hatphi,
                 const unsigned short* __restrict__ phimu,
                 const float* __restrict__ plusT,
                 const float* __restrict__ seq,
                 float* __restrict__ out) {
    const int n = (int)blockIdx.x + 1;
    const int bblk = (int)blockIdx.y;
    const int t = threadIdx.x, wv = t >> 6, lane = t & 63, half = lane >> 5, r = lane & 31;

    __shared__ float s_plus[NM];
    __shared__ float dsum[4][64];
    __shared__ float nsum[4][64];

    bf16x8 q[2][4];
    {
        const unsigned short* qb = hatphi + (size_t)(n - 1) * NB * NH;
#pragma unroll
        for (int bs = 0; bs < 2; bs++)
#pragma unroll
            for (int kq = 0; kq < 4; kq++)
                q[bs][kq] = *(const bf16x8*)(qb + (bblk * 64 + bs * 32 + r) * NH + kq * 16 + half * 8);
    }
    // prefetch p tile 0
    bf16x8 p[4];
#pragma unroll
    for (int kq = 0; kq < 4; kq++)
        p[kq] = *(const bf16x8*)(phimu + (wv * 32 + r) * NH + kq * 16 + half * 8);
    // stage plus row (one dwordx4 per thread)
    *(f32x4*)(s_plus + t * 4) = *(const f32x4*)(plusT + n * NM + t * 4);
    __syncthreads();

    f32x4 den0 = {0.f,0.f,0.f,0.f}, num0 = {0.f,0.f,0.f,0.f};
    f32x4 den1 = {0.f,0.f,0.f,0.f}, num1 = {0.f,0.f,0.f,0.f};

    for (int it = 0; it < 8; ++it) {
        const int mb = it * 128 + wv * 32;
        bf16x8 pn[4];
        if (it < 7) {   // prefetch next tile (no barrier in loop: stays in flight)
#pragma unroll
            for (int kq = 0; kq < 4; kq++)
                pn[kq] = *(const bf16x8*)(phimu + (mb + 128 + r) * NH + kq * 16 + half * 8);
        }
        f32x16 a0, a1;
#pragma unroll
        for (int i = 0; i < 16; i++) { a0[i] = 0.f; a1[i] = 0.f; }
#pragma unroll
        for (int kq = 0; kq < 4; kq++) {
            a0 = __builtin_amdgcn_mfma_f32_32x32x16_bf16(p[kq], q[0][kq], a0, 0, 0, 0);
            a1 = __builtin_amdgcn_mfma_f32_32x32x16_bf16(p[kq], q[1][kq], a1, 0, 0, 0);
        }
        f32x4 pv[4];
#pragma unroll
        for (int g = 0; g < 4; g++) pv[g] = *(const f32x4*)(s_plus + mb + 4 * half + 8 * g);
#pragma unroll
        for (int g = 0; g < 4; g++) {
            f32x4 e0, e1;
#pragma unroll
            for (int j = 0; j < 4; j++) {
                e0[j] = EXP2F(a0[4 * g + j]);    // m = mb + j + 8*g + 4*half
                e1[j] = EXP2F(a1[4 * g + j]);
            }
            den0 += e0; num0 += e0 * pv[g];
            den1 += e1; num1 += e1 * pv[g];
        }
        if (it < 7) {
#pragma unroll
            for (int kq = 0; kq < 4; kq++) p[kq] = pn[kq];
        }
    }
    float d0 = (den0[0] + den0[1]) + (den0[2] + den0[3]);
    float nu0 = (num0[0] + num0[1]) + (num0[2] + num0[3]);
    float d1 = (den1[0] + den1[1]) + (den1[2] + den1[3]);
    float nu1 = (num1[0] + num1[1]) + (num1[2] + num1[3]);
    // combine the two m-halves (same b, complementary m rows)
    d0 += __shfl_xor(d0, 32); nu0 += __shfl_xor(nu0, 32);
    d1 += __shfl_xor(d1, 32); nu1 += __shfl_xor(nu1, 32);

    if (half == 0) {
        dsum[wv][r] = d0; dsum[wv][32 + r] = d1;
        nsum[wv][r] = nu0; nsum[wv][32 + r] = nu1;
    }
    __syncthreads();
    if (t < 64) {
        float d  = (dsum[0][t] + dsum[1][t]) + (dsum[2][t] + dsum[3][t]);
        float nu = (nsum[0][t] + nsum[1][t]) + (nsum[2][t] + nsum[3][t]);
        float p2 = nu / d;
        p2 = fminf(fmaxf(p2, 1e-6f), 1.0f - 1e-6f);
        float tg = seq[(size_t)(bblk * 64 + t) * NPOS + n];
        float bce = (tg > 0.f) ? -logf(p2) : -logf(1.0f - p2);
#pragma unroll
        for (int o = 32; o; o >>= 1) bce += __shfl_xor(bce, o);
        if (t == 0) atomicAdd(out, bce * (1.0f / 130816.0f));  // / (B*(N-1))
    }
}

extern "C" void kernel_launch(void* const* d_in, const int* in_sizes, int n_in,
                              void* d_out, int out_size, void* d_ws, size_t ws_size,
                              hipStream_t stream) {
    const float* seq = (const float*)d_in[0];  // (B,N)
    const float* mem = (const float*)d_in[1];  // (M,N)
    const float* Al  = (const float*)d_in[2];  // (N,H,N)
    const float* Bl  = (const float*)d_in[3];  // (H,N)

    char* ws = (char*)d_ws;
    unsigned short* seq_bf = (unsigned short*)(ws + 0);          // 256 KB
    float*          BnT    = (float*)(ws + 262144);              // 128 KB (N,H)
    unsigned short* phimu  = (unsigned short*)(ws + 393216);     // 128 KB (M,H) *log2e
    float*          plusT  = (float*)(ws + 524288);              // 2 MB (N,M)
    unsigned short* hatphi = (unsigned short*)(ws + 2621440);    // 16.7 MB (N-1,B,H)
    float*          outp   = (float*)d_out;

    k0_seq_bf16<<<128, 256, 0, stream>>>(seq, seq_bf, outp);
    k1a_bnT<<<64, 64, 0, stream>>>(Bl, BnT);
    k1b_phimu<<<512, 256, 0, stream>>>(BnT, mem, phimu);
    k1c_plusT<<<128, 256, 0, stream>>>(mem, plusT);
    k2_hatphi<<<dim3(2, 511), 256, 0, stream>>>(Al, seq_bf, hatphi);
    k3_retrieve<<<dim3(511, 4), 256, 0, stream>>>(hatphi, phimu, plusT, seq, outp);
}

// Round 6
// 145.213 us; speedup vs baseline: 1.3844x; 1.1353x over previous
//
#include <hip/hip_runtime.h>
#include <stdint.h>

// Problem constants (fixed by reference setup_inputs)
#define NPOS 512   // N
#define NH   64    // H
#define NM   1024  // M
#define NB   256   // B
#define NM1  511   // N-1

typedef __attribute__((ext_vector_type(8)))  short bf16x8;
typedef __attribute__((ext_vector_type(16))) float f32x16;
typedef __attribute__((ext_vector_type(4)))  float f32x4;
typedef __attribute__((ext_vector_type(4)))  int   i32x4;

#if __has_builtin(__builtin_amdgcn_exp2f)
#define EXP2F(x) __builtin_amdgcn_exp2f(x)
#else
#define EXP2F(x) __expf((x) * 0.69314718055994531f)
#endif

__device__ __forceinline__ unsigned short f2bf(float x) {
    unsigned u = __float_as_uint(x);
    u = (u + 0x7FFFu + ((u >> 16) & 1u)) >> 16;   // RNE
    return (unsigned short)u;
}
__device__ __forceinline__ int pack2(unsigned short a, unsigned short b) {
    return (int)a | ((int)b << 16);
}

// ---------------- kA: fused prep = {k0 seq->bf16 + zero out, k1a BnT softmax,
//                  k1c plusT transpose}. 272 blocks x 256 thr. ----------------
__global__ __launch_bounds__(256, 4)
void kA_prep(const float* __restrict__ seq, const float* __restrict__ Bl,
             const float* __restrict__ mem,
             unsigned short* __restrict__ seq_bf, float* __restrict__ BnT,
             float* __restrict__ plusT, float* __restrict__ out) {
    const int bid = blockIdx.x, t = threadIdx.x;
    if (bid < 128) {
        // --- k0: sequences fp32 -> bf16 (exact for +/-1) ---
        if (bid == 0 && t == 0) out[0] = 0.f;
        int idx = (bid * 256 + t) * 4;
        f32x4 v = *(const f32x4*)(seq + idx);
        int2 o;
        o.x = pack2(f2bf(v.x), f2bf(v.y));
        o.y = pack2(f2bf(v.z), f2bf(v.w));
        *(int2*)(seq_bf + idx) = o;
    } else if (bid < 144) {
        // --- k1a: Bn = softmax(B_logits, axis=-1), stored transposed ---
        const int h = (bid - 128) * 4 + (t >> 6), l = t & 63;
        float v[8]; float mx = -1e30f;
#pragma unroll
        for (int j = 0; j < 8; j++) { v[j] = Bl[h * NPOS + l + 64 * j]; mx = fmaxf(mx, v[j]); }
#pragma unroll
        for (int o = 32; o; o >>= 1) mx = fmaxf(mx, __shfl_xor(mx, o));
        float s = 0.f;
#pragma unroll
        for (int j = 0; j < 8; j++) { v[j] = __expf(v[j] - mx); s += v[j]; }
#pragma unroll
        for (int o = 32; o; o >>= 1) s += __shfl_xor(s, o);
        float r = 1.0f / s;
#pragma unroll
        for (int j = 0; j < 8; j++) BnT[(l + 64 * j) * NH + h] = v[j] * r;
    } else {
        // --- k1c: plusT[n][m] via LDS 64x64 tile transpose ---
        __shared__ float sT[64][65];
        const int bb = bid - 144;
        const int mt = bb >> 3, nt = bb & 7;
        const int rr = t >> 2, cc = t & 3;
        const float* src = mem + (size_t)(mt * 64 + rr) * NPOS + nt * 64 + cc * 16;
#pragma unroll
        for (int j = 0; j < 4; j++) {
            f32x4 v = *(const f32x4*)(src + j * 4);
            sT[rr][cc * 16 + j * 4 + 0] = (v.x > 0.f) ? 1.f : 0.f;
            sT[rr][cc * 16 + j * 4 + 1] = (v.y > 0.f) ? 1.f : 0.f;
            sT[rr][cc * 16 + j * 4 + 2] = (v.z > 0.f) ? 1.f : 0.f;
            sT[rr][cc * 16 + j * 4 + 3] = (v.w > 0.f) ? 1.f : 0.f;
        }
        __syncthreads();
        float* dst = plusT + (size_t)(nt * 64 + rr) * NM + mt * 64 + cc * 16;
#pragma unroll
        for (int j = 0; j < 4; j++) {
            f32x4 o;
            o.x = sT[cc * 16 + j * 4 + 0][rr];
            o.y = sT[cc * 16 + j * 4 + 1][rr];
            o.z = sT[cc * 16 + j * 4 + 2][rr];
            o.w = sT[cc * 16 + j * 4 + 3][rr];
            *(f32x4*)(dst + j * 4) = o;
        }
    }
}

// ---------------- k1b: phi_mu[m,h] = sum_n Bn[h,n]*memory[m,n] -> bf16 -------
// 512 blocks x 2 m-rows, 4 independent fma chains. PRE-SCALED by log2(e).
__global__ __launch_bounds__(256, 4)
void k1b_phimu(const float* __restrict__ BnT, const float* __restrict__ mem,
               unsigned short* __restrict__ phimu) {
    const int m0 = blockIdx.x * 2, t = threadIdx.x;
    __shared__ float mrow[2][NPOS];
    __shared__ float part[2][256];
    {
        int row = t >> 7, c = (t & 127) * 4;
        *(f32x4*)(&mrow[row][c]) = *(const f32x4*)(mem + (size_t)(m0 + row) * NPOS + c);
    }
    __syncthreads();
    const int h = t & 63, seg = t >> 6;
    float a[2] = {0.f, 0.f};
    float b2[2] = {0.f, 0.f};
    const float* bp = BnT + seg * 128 * NH + h;
#pragma unroll 8
    for (int nn = 0; nn < 128; nn += 2) {
        float x0 = bp[nn * NH], x1 = bp[(nn + 1) * NH];
#pragma unroll
        for (int row = 0; row < 2; row++) {
            a[row]  = fmaf(x0, mrow[row][seg * 128 + nn], a[row]);
            b2[row] = fmaf(x1, mrow[row][seg * 128 + nn + 1], b2[row]);
        }
    }
#pragma unroll
    for (int row = 0; row < 2; row++) part[row][t] = a[row] + b2[row];
    __syncthreads();
    if (t < 64) {
#pragma unroll
        for (int row = 0; row < 2; row++) {
            float s = (part[row][t] + part[row][t + 64]) + (part[row][t + 128] + part[row][t + 192]);
            phimu[(m0 + row) * NH + t] = f2bf(s * 1.4426950408889634f);  // * log2(e)
        }
    }
}

// ---------------- k23: FUSED hat_phi + retrieval softmax + BCE ---------------
// grid 511 (one block per n), 256 thr = 4 waves.
// Phase 1 (K2): masked-softmax(A_logits[n]) GEMM seq -> hat_phi 256b x 64h in LDS.
// Phase 2 (K3): wave wv owns 64 b; loops 32 m-tiles of 32 (p prefetched 1 ahead),
//               exp2 streaming softmax (phimu pre-scaled by log2e), BCE epilogue.
__global__ __launch_bounds__(256, 2)
void k23_fused(const float* __restrict__ Al, const unsigned short* __restrict__ seq_bf,
               const unsigned short* __restrict__ phimu, const float* __restrict__ plusT,
               const float* __restrict__ seq, float* __restrict__ out) {
    __shared__ __align__(16) unsigned short s_lds[256 * 72];  // S tile -> q tile
    __shared__ __align__(16) unsigned short e_lds[64 * 72];   // E tile -> dsum/nsum
    __shared__ float z_lds[64];                               // row sums Z[h] -> wave partials
    __shared__ float s_plus[NM];

    const int t = threadIdx.x;
    const int n = NM1 - (int)blockIdx.x;          // n in 1..511, big n first
    const int ksteps = (n + 63) >> 6;
    const int wv = t >> 6, lane = t & 63, half = lane >> 5, r = lane & 31;

    if (t < 64) z_lds[t] = 0.f;
    // stage plus row early (independent of phase 1)
    *(f32x4*)(s_plus + t * 4) = *(const f32x4*)(plusT + n * NM + t * 4);

    // ================= phase 1: hat_phi tile =================
    const int eh = t >> 2, ei = (t & 3) * 16;
    const float* arow = Al + ((size_t)n * NH + eh) * NPOS + ei;
    const unsigned short* srcS = seq_bf + (size_t)t * NPOS;

    f32x16 acc00, acc01, acc10, acc11;
#pragma unroll
    for (int i = 0; i < 16; i++) { acc00[i] = 0.f; acc01[i] = 0.f; acc10[i] = 0.f; acc11[i] = 0.f; }

    f32x4 ea[4]; i32x4 sa[8];
#pragma unroll
    for (int g = 0; g < 4; g++) ea[g] = *(const f32x4*)(arow + g * 4);
#pragma unroll
    for (int c = 0; c < 8; c++) sa[c] = *(const i32x4*)(srcS + c * 8);
    __syncthreads();   // z_lds init + s_plus staged

    for (int kk = 0; kk < ksteps; kk++) {
        const int k0 = kk * 64;
        // exp + stage E tile from regs
        {
            float zp = 0.f;
            unsigned short* ep = e_lds + eh * 72 + ei;
#pragma unroll
            for (int g = 0; g < 4; g++) {
                int i0 = k0 + ei + g * 4;
                float e0 = (i0 + 0 < n) ? __expf(ea[g].x) : 0.f;
                float e1 = (i0 + 1 < n) ? __expf(ea[g].y) : 0.f;
                float e2 = (i0 + 2 < n) ? __expf(ea[g].z) : 0.f;
                float e3 = (i0 + 3 < n) ? __expf(ea[g].w) : 0.f;
                zp += (e0 + e1) + (e2 + e3);
                int2 o; o.x = pack2(f2bf(e0), f2bf(e1)); o.y = pack2(f2bf(e2), f2bf(e3));
                *(int2*)(ep + g * 4) = o;
            }
            zp += __shfl_xor(zp, 1);
            zp += __shfl_xor(zp, 2);
            if ((t & 3) == 0) z_lds[eh] += zp;
        }
        // stage S tile from regs (thread t owns row t)
        {
            unsigned short* dp = s_lds + t * 72;
#pragma unroll
            for (int c = 0; c < 8; c++) *(i32x4*)(dp + c * 8) = sa[c];
        }
        __syncthreads();
        // prefetch k+1 (in flight during MFMA phase)
        if (kk + 1 < ksteps) {
#pragma unroll
            for (int g = 0; g < 4; g++) ea[g] = *(const f32x4*)(arow + k0 + 64 + g * 4);
#pragma unroll
            for (int c = 0; c < 8; c++) sa[c] = *(const i32x4*)(srcS + k0 + 64 + c * 8);
        }
        // MFMA: D[b][h] += S[b,i] * E[h,i]
        {
            const unsigned short* sA0 = s_lds + (wv * 64 + r) * 72;
            const unsigned short* sA1 = sA0 + 32 * 72;
            const unsigned short* sB0 = e_lds + r * 72;
            const unsigned short* sB1 = sB0 + 32 * 72;
#pragma unroll
            for (int kq = 0; kq < 4; kq++) {
                const int ko = kq * 16 + half * 8;
                bf16x8 A0 = *(const bf16x8*)(sA0 + ko);
                bf16x8 A1 = *(const bf16x8*)(sA1 + ko);
                bf16x8 B0 = *(const bf16x8*)(sB0 + ko);
                bf16x8 B1 = *(const bf16x8*)(sB1 + ko);
                acc00 = __builtin_amdgcn_mfma_f32_32x32x16_bf16(A0, B0, acc00, 0, 0, 0);
                acc01 = __builtin_amdgcn_mfma_f32_32x32x16_bf16(A0, B1, acc01, 0, 0, 0);
                acc10 = __builtin_amdgcn_mfma_f32_32x32x16_bf16(A1, B0, acc10, 0, 0, 0);
                acc11 = __builtin_amdgcn_mfma_f32_32x32x16_bf16(A1, B1, acc11, 0, 0, 0);
            }
        }
        __syncthreads();
    }
    // epilogue: scale by 1/Z[h], write q tile (b rows, stride 72) into s_lds
    {
        float rz0 = 1.0f / z_lds[r];
        float rz1 = 1.0f / z_lds[32 + r];
#pragma unroll
        for (int reg = 0; reg < 16; reg++) {
            int row = (reg & 3) + 8 * (reg >> 2) + 4 * half;
            s_lds[(wv * 64 + row) * 72 + r]            = f2bf(acc00[reg] * rz0);
            s_lds[(wv * 64 + row) * 72 + 32 + r]       = f2bf(acc01[reg] * rz1);
            s_lds[(wv * 64 + 32 + row) * 72 + r]       = f2bf(acc10[reg] * rz0);
            s_lds[(wv * 64 + 32 + row) * 72 + 32 + r]  = f2bf(acc11[reg] * rz1);
        }
    }
    __syncthreads();

    // ================= phase 2: retrieval softmax =================
    // p tile 0 (global, issue first so it overlaps the q LDS reads)
    bf16x8 p[4];
#pragma unroll
    for (int kq = 0; kq < 4; kq++)
        p[kq] = *(const bf16x8*)(phimu + (r) * NH + kq * 16 + half * 8);
    // q fragments for this wave's 64 b (held in regs for all 32 m-tiles)
    bf16x8 q[2][4];
#pragma unroll
    for (int bs = 0; bs < 2; bs++)
#pragma unroll
        for (int kq = 0; kq < 4; kq++)
            q[bs][kq] = *(const bf16x8*)(s_lds + (wv * 64 + bs * 32 + r) * 72 + kq * 16 + half * 8);

    f32x4 den0 = {0.f,0.f,0.f,0.f}, num0 = {0.f,0.f,0.f,0.f};
    f32x4 den1 = {0.f,0.f,0.f,0.f}, num1 = {0.f,0.f,0.f,0.f};

    for (int it = 0; it < 32; ++it) {
        bf16x8 pn[4];
        if (it < 31) {   // prefetch next m-tile (no barrier in loop: stays in flight)
#pragma unroll
            for (int kq = 0; kq < 4; kq++)
                pn[kq] = *(const bf16x8*)(phimu + ((it + 1) * 32 + r) * NH + kq * 16 + half * 8);
        }
        f32x16 a0, a1;
#pragma unroll
        for (int i = 0; i < 16; i++) { a0[i] = 0.f; a1[i] = 0.f; }
#pragma unroll
        for (int kq = 0; kq < 4; kq++) {
            a0 = __builtin_amdgcn_mfma_f32_32x32x16_bf16(p[kq], q[0][kq], a0, 0, 0, 0);
            a1 = __builtin_amdgcn_mfma_f32_32x32x16_bf16(p[kq], q[1][kq], a1, 0, 0, 0);
        }
        const int mb = it * 32;
        f32x4 pv[4];
#pragma unroll
        for (int g = 0; g < 4; g++) pv[g] = *(const f32x4*)(s_plus + mb + 4 * half + 8 * g);
#pragma unroll
        for (int g = 0; g < 4; g++) {
            f32x4 e0, e1;
#pragma unroll
            for (int j = 0; j < 4; j++) {
                e0[j] = EXP2F(a0[4 * g + j]);    // m = mb + j + 8*g + 4*half
                e1[j] = EXP2F(a1[4 * g + j]);
            }
            den0 += e0; num0 += e0 * pv[g];
            den1 += e1; num1 += e1 * pv[g];
        }
        if (it < 31) {
#pragma unroll
            for (int kq = 0; kq < 4; kq++) p[kq] = pn[kq];
        }
    }
    float d0 = (den0[0] + den0[1]) + (den0[2] + den0[3]);
    float nu0 = (num0[0] + num0[1]) + (num0[2] + num0[3]);
    float d1 = (den1[0] + den1[1]) + (den1[2] + den1[3]);
    float nu1 = (num1[0] + num1[1]) + (num1[2] + num1[3]);
    // combine the two m-halves (same b, complementary m rows)
    d0 += __shfl_xor(d0, 32); nu0 += __shfl_xor(nu0, 32);
    d1 += __shfl_xor(d1, 32); nu1 += __shfl_xor(nu1, 32);

    // per-b results: wave wv owns b = wv*64 + bs*32 + r (all m done inside wave)
    float* dsum = (float*)e_lds;          // 256 floats (e_lds dead after phase 1)
    float* nsum = dsum + 256;
    if (half == 0) {
        dsum[wv * 64 + r]      = d0; nsum[wv * 64 + r]      = nu0;
        dsum[wv * 64 + 32 + r] = d1; nsum[wv * 64 + 32 + r] = nu1;
    }
    __syncthreads();
    // BCE for b = t
    {
        float dd = dsum[t], nn = nsum[t];
        float p2 = nn / dd;
        p2 = fminf(fmaxf(p2, 1e-6f), 1.0f - 1e-6f);
        float tg = seq[(size_t)t * NPOS + n];
        float bce = (tg > 0.f) ? -logf(p2) : -logf(1.0f - p2);
#pragma unroll
        for (int o = 32; o; o >>= 1) bce += __shfl_xor(bce, o);
        if (lane == 0) z_lds[wv] = bce;   // z_lds reusable (rz consumed in epilogue)
    }
    __syncthreads();
    if (t == 0)
        atomicAdd(out, (z_lds[0] + z_lds[1] + z_lds[2] + z_lds[3]) * (1.0f / 130816.0f));
}

extern "C" void kernel_launch(void* const* d_in, const int* in_sizes, int n_in,
                              void* d_out, int out_size, void* d_ws, size_t ws_size,
                              hipStream_t stream) {
    const float* seq = (const float*)d_in[0];  // (B,N)
    const float* mem = (const float*)d_in[1];  // (M,N)
    const float* Al  = (const float*)d_in[2];  // (N,H,N)
    const float* Bl  = (const float*)d_in[3];  // (H,N)

    char* ws = (char*)d_ws;
    unsigned short* seq_bf = (unsigned short*)(ws + 0);          // 256 KB
    float*          BnT    = (float*)(ws + 262144);              // 128 KB (N,H)
    unsigned short* phimu  = (unsigned short*)(ws + 393216);     // 128 KB (M,H) *log2e
    float*          plusT  = (float*)(ws + 524288);              // 2 MB (N,M)
    float*          outp   = (float*)d_out;

    kA_prep<<<272, 256, 0, stream>>>(seq, Bl, mem, seq_bf, BnT, plusT, outp);
    k1b_phimu<<<512, 256, 0, stream>>>(BnT, mem, phimu);
    k23_fused<<<511, 256, 0, stream>>>(Al, seq_bf, phimu, plusT, seq, outp);
}